// Round 1
// baseline (449.670 us; speedup 1.0000x reference)
//
#include <hip/hip_runtime.h>
#include <cstdint>

#define EPS 1e-6f

constexpr int Bsz = 4, Hn = 16, Lseq = 8192, Dd = 64;
constexpr int BH = Bsz * Hn;              // 64
constexpr int CHUNK = 128;                // rows per wave-chunk
constexpr int CPB = Lseq / CHUNK;         // 64 chunks per (b,h)
constexpr int NCHUNKS = BH * CPB;         // 4096
constexpr int WPB = 4;                    // waves per block

// feature map: x>0 ? x+1 : exp(x). __expf -> v_exp_f32 (cheap, ~1 ULP)
__device__ __forceinline__ float phi(float x) {
    return x > 0.0f ? x + 1.0f : __expf(x);
}

// ---------------- kernel 1: per-chunk aggregates (order-free) ----------------
__global__ __launch_bounds__(256) void partials_kernel(
    const float* __restrict__ k, const float* __restrict__ v,
    const float* __restrict__ mask,
    float* __restrict__ pk, float* __restrict__ pkv)
{
    const int wave = blockIdx.x * WPB + (threadIdx.x >> 6);
    const int lane = threadIdx.x & 63;
    const int rg = lane >> 4;          // row group 0..3
    const int dg = lane & 15;          // dim group: dims [4*dg, 4*dg+4)
    const int bh = wave / CPB;
    const int c  = wave % CPB;
    const int b  = bh / Hn;
    const int l0 = c * CHUNK;

    float4 ak  = make_float4(0.f, 0.f, 0.f, 0.f);
    float4 akv = make_float4(0.f, 0.f, 0.f, 0.f);

    for (int i = 0; i < CHUNK; i += 4) {
        const int l = l0 + i + rg;
        const size_t off = ((size_t)bh * Lseq + l) * Dd + dg * 4;
        const float4 k4 = *(const float4*)(k + off);
        const float4 v4 = *(const float4*)(v + off);
        const float m = mask[(size_t)b * Lseq + l];
        float t;
        t = phi(k4.x) * m; ak.x += t; akv.x += t * (v4.x * m);
        t = phi(k4.y) * m; ak.y += t; akv.y += t * (v4.y * m);
        t = phi(k4.z) * m; ak.z += t; akv.z += t * (v4.z * m);
        t = phi(k4.w) * m; ak.w += t; akv.w += t * (v4.w * m);
    }

    // reduce across the 4 row groups (xor 16, 32) — butterfly: all lanes get total
    #pragma unroll
    for (int off = 16; off <= 32; off <<= 1) {
        ak.x  += __shfl_xor(ak.x,  off, 64);
        ak.y  += __shfl_xor(ak.y,  off, 64);
        ak.z  += __shfl_xor(ak.z,  off, 64);
        ak.w  += __shfl_xor(ak.w,  off, 64);
        akv.x += __shfl_xor(akv.x, off, 64);
        akv.y += __shfl_xor(akv.y, off, 64);
        akv.z += __shfl_xor(akv.z, off, 64);
        akv.w += __shfl_xor(akv.w, off, 64);
    }

    if (rg == 0) {
        const size_t o = (size_t)wave * Dd + dg * 4;
        *(float4*)(pk  + o) = ak;
        *(float4*)(pkv + o) = akv;
    }
}

// ------------- kernel 2: exclusive scan over chunk aggregates (tiny) ---------
__global__ __launch_bounds__(64) void scan_kernel(
    float* __restrict__ pk, float* __restrict__ pkv)
{
    const int bh = blockIdx.x;
    const int d  = threadIdx.x;
    float rk = 0.f, rkv = 0.f;
    for (int c = 0; c < CPB; ++c) {
        const size_t o = ((size_t)(bh * CPB + c)) * Dd + d;
        const float tk = pk[o], tkv = pkv[o];
        pk[o]  = rk;  rk  += tk;
        pkv[o] = rkv; rkv += tkv;
    }
}

// ---------------- kernel 3: final pass with exact inclusive prefix -----------
__global__ __launch_bounds__(256) void final_kernel(
    const float* __restrict__ q, const float* __restrict__ k,
    const float* __restrict__ v, const float* __restrict__ mask,
    const float* __restrict__ pk, const float* __restrict__ pkv,
    float* __restrict__ out)
{
    const int wave = blockIdx.x * WPB + (threadIdx.x >> 6);
    const int lane = threadIdx.x & 63;
    const int rg = lane >> 4;
    const int dg = lane & 15;
    const int bh = wave / CPB;
    const int c  = wave % CPB;
    const int b  = bh / Hn;
    const int l0 = c * CHUNK;

    const size_t po = (size_t)wave * Dd + dg * 4;
    float4 Sk  = *(const float4*)(pk  + po);   // exclusive prefix for this chunk
    float4 Skv = *(const float4*)(pkv + po);

    for (int i = 0; i < CHUNK; i += 4) {
        const int l = l0 + i + rg;
        const size_t off = ((size_t)bh * Lseq + l) * Dd + dg * 4;
        const float4 q4 = *(const float4*)(q + off);
        const float4 k4 = *(const float4*)(k + off);
        const float4 v4 = *(const float4*)(v + off);
        const float m = mask[(size_t)b * Lseq + l];

        float4 fq, a, akv;
        fq.x = phi(q4.x); fq.y = phi(q4.y); fq.z = phi(q4.z); fq.w = phi(q4.w);
        a.x = phi(k4.x) * m; akv.x = a.x * (v4.x * m);
        a.y = phi(k4.y) * m; akv.y = a.y * (v4.y * m);
        a.z = phi(k4.z) * m; akv.z = a.z * (v4.z * m);
        a.w = phi(k4.w) * m; akv.w = a.w * (v4.w * m);

        // inclusive scan across the 4 row groups (Hillis-Steele, stride 16, 32)
        float t;
        t = __shfl_up(a.x,  16, 64); if (rg >= 1) a.x  += t;
        t = __shfl_up(a.y,  16, 64); if (rg >= 1) a.y  += t;
        t = __shfl_up(a.z,  16, 64); if (rg >= 1) a.z  += t;
        t = __shfl_up(a.w,  16, 64); if (rg >= 1) a.w  += t;
        t = __shfl_up(akv.x,16, 64); if (rg >= 1) akv.x += t;
        t = __shfl_up(akv.y,16, 64); if (rg >= 1) akv.y += t;
        t = __shfl_up(akv.z,16, 64); if (rg >= 1) akv.z += t;
        t = __shfl_up(akv.w,16, 64); if (rg >= 1) akv.w += t;
        t = __shfl_up(a.x,  32, 64); if (rg >= 2) a.x  += t;
        t = __shfl_up(a.y,  32, 64); if (rg >= 2) a.y  += t;
        t = __shfl_up(a.z,  32, 64); if (rg >= 2) a.z  += t;
        t = __shfl_up(a.w,  32, 64); if (rg >= 2) a.w  += t;
        t = __shfl_up(akv.x,32, 64); if (rg >= 2) akv.x += t;
        t = __shfl_up(akv.y,32, 64); if (rg >= 2) akv.y += t;
        t = __shfl_up(akv.z,32, 64); if (rg >= 2) akv.z += t;
        t = __shfl_up(akv.w,32, 64); if (rg >= 2) akv.w += t;

        const float4 ik  = make_float4(Sk.x + a.x,  Sk.y + a.y,  Sk.z + a.z,  Sk.w + a.w);
        const float4 ikv = make_float4(Skv.x + akv.x, Skv.y + akv.y, Skv.z + akv.z, Skv.w + akv.w);

        // z = (sum_d phi(q)*k_cumsum + EPS) * mask  (reduce over 16 dg lanes)
        float p = fq.x * ik.x + fq.y * ik.y + fq.z * ik.z + fq.w * ik.w;
        p += __shfl_xor(p, 1, 64);
        p += __shfl_xor(p, 2, 64);
        p += __shfl_xor(p, 4, 64);
        p += __shfl_xor(p, 8, 64);
        const float z = (p + EPS) * m;
        const float inv = 1.0f / z;

        float4 o4;
        o4.x = fq.x * ikv.x * inv;
        o4.y = fq.y * ikv.y * inv;
        o4.z = fq.z * ikv.z * inv;
        o4.w = fq.w * ikv.w * inv;
        *(float4*)(out + off) = o4;

        // advance running prefix by the 4-row total (inclusive value at rg==3)
        Sk.x  += __shfl(a.x,  48 + dg, 64);
        Sk.y  += __shfl(a.y,  48 + dg, 64);
        Sk.z  += __shfl(a.z,  48 + dg, 64);
        Sk.w  += __shfl(a.w,  48 + dg, 64);
        Skv.x += __shfl(akv.x, 48 + dg, 64);
        Skv.y += __shfl(akv.y, 48 + dg, 64);
        Skv.z += __shfl(akv.z, 48 + dg, 64);
        Skv.w += __shfl(akv.w, 48 + dg, 64);
    }
}

extern "C" void kernel_launch(void* const* d_in, const int* in_sizes, int n_in,
                              void* d_out, int out_size, void* d_ws, size_t ws_size,
                              hipStream_t stream) {
    const float* q    = (const float*)d_in[0];
    const float* k    = (const float*)d_in[1];
    const float* v    = (const float*)d_in[2];
    const float* mask = (const float*)d_in[3];
    float* out = (float*)d_out;

    // workspace: 2 arrays of NCHUNKS*64 floats = 2 MiB total
    float* pk  = (float*)d_ws;
    float* pkv = pk + (size_t)NCHUNKS * Dd;

    partials_kernel<<<NCHUNKS / WPB, 256, 0, stream>>>(k, v, mask, pk, pkv);
    scan_kernel<<<BH, 64, 0, stream>>>(pk, pkv);
    final_kernel<<<NCHUNKS / WPB, 256, 0, stream>>>(q, k, v, mask, pk, pkv, out);
}